// Round 5
// baseline (294.561 us; speedup 1.0000x reference)
//
#include <hip/hip_runtime.h>
#include <math.h>

// Problem constants (from reference)
#define BB 16
#define VV 6890
#define NFF 13776
#define HH 512
#define WW 512
// SIGMA = 1e-4 -> 1/SIGMA = 1e4

typedef float nf4 __attribute__((ext_vector_type(4)));  // native vec4 for nontemporal st
typedef int   ni4 __attribute__((ext_vector_type(4)));

#define GEOT 1024

// ---------------------------------------------------------------------------
// Fused geometry kernel.
// Block 0: build CSR (vertex->face adjacency) entirely in LDS:
//   histogram (LDS atomics) -> block scan -> fill (LDS cursors).
// Blocks 1..: per-(batch,face) face normals -> fn4.
// The two halves are independent; they share one dispatch.
// ---------------------------------------------------------------------------
__global__ __launch_bounds__(GEOT) void k_geo(const float* __restrict__ verts,
                                              const int* __restrict__ faces,
                                              float4* __restrict__ fn4,
                                              int* __restrict__ offsets,
                                              int* __restrict__ adj) {
    int blk = blockIdx.x;
    if (blk == 0) {
        __shared__ int hist[VV];      // 27.6 KB
        __shared__ int part[GEOT];    // 4 KB
        int t = threadIdx.x;
        for (int v = t; v < VV; v += GEOT) hist[v] = 0;
        __syncthreads();
        for (int e = t; e < NFF * 3; e += GEOT) atomicAdd(&hist[faces[e]], 1);
        __syncthreads();
        // exclusive scan of hist[VV]
        const int CH = (VV + GEOT - 1) / GEOT;  // 7
        int base = t * CH;
        int local = 0;
        for (int k = 0; k < CH; k++) { int idx = base + k; if (idx < VV) local += hist[idx]; }
        part[t] = local;
        __syncthreads();
        for (int off = 1; off < GEOT; off <<= 1) {
            int v = part[t];
            int add = (t >= off) ? part[t - off] : 0;
            __syncthreads();
            part[t] = v + add;
            __syncthreads();
        }
        int running = (t == 0) ? 0 : part[t - 1];
        for (int k = 0; k < CH; k++) {
            int idx = base + k;
            if (idx < VV) {
                int c = hist[idx];
                hist[idx] = running;      // becomes the fill cursor
                offsets[idx] = running;
                running += c;
            }
        }
        if (t == 0) offsets[VV] = NFF * 3;
        __syncthreads();
        // fill adjacency using LDS cursors
        for (int e = t; e < NFF * 3; e += GEOT) {
            int v = faces[e];
            int pos = atomicAdd(&hist[v], 1);
            adj[pos] = e / 3;  // face id
        }
    } else {
        int i = (blk - 1) * GEOT + threadIdx.x;
        if (i >= BB * NFF) return;
        int b = i / NFF;
        int f = i - b * NFF;
        int i0 = faces[3 * f + 0];
        int i1 = faces[3 * f + 1];
        int i2 = faces[3 * f + 2];
        const float* vb = verts + (size_t)b * (VV * 3);
        float ax = vb[3 * i0 + 0], ay = vb[3 * i0 + 1], az = vb[3 * i0 + 2];
        float bx = vb[3 * i1 + 0], by = vb[3 * i1 + 1], bz = vb[3 * i1 + 2];
        float cx = vb[3 * i2 + 0], cy = vb[3 * i2 + 1], cz = vb[3 * i2 + 2];
        float e1x = bx - ax, e1y = by - ay, e1z = bz - az;
        float e2x = cx - ax, e2y = cy - ay, e2z = cz - az;
        float4 n;
        n.x = e1y * e2z - e1z * e2y;
        n.y = e1z * e2x - e1x * e2z;
        n.z = e1x * e2y - e1y * e2x;
        n.w = 0.f;
        fn4[i] = n;
    }
}

// ---------------------------------------------------------------------------
// Per-(batch,vertex): gather adjacent face normals via CSR, normalize.
// ---------------------------------------------------------------------------
__global__ __launch_bounds__(256) void k_vn(const float4* __restrict__ fn4,
                                            const int* __restrict__ offsets,
                                            const int* __restrict__ adj,
                                            float4* __restrict__ vn4) {
    int i = blockIdx.x * 256 + threadIdx.x;
    if (i >= BB * VV) return;
    int b = i / VV;
    int v = i - b * VV;
    int s = offsets[v], e = offsets[v + 1];
    float x = 0.f, y = 0.f, z = 0.f;
    const float4* fnb = fn4 + (size_t)b * NFF;
    for (int j = s; j < e; j++) {
        float4 n = fnb[adj[j]];
        x += n.x; y += n.y; z += n.z;
    }
    float inv = 1.0f / fmaxf(sqrtf(x * x + y * y + z * z), 1e-6f);
    float4 o; o.x = x * inv; o.y = y * inv; o.z = z * inv; o.w = 0.f;
    vn4[i] = o;
}

// ---------------------------------------------------------------------------
// face_attr_sum[b,f] = sum of the 3 normalized vertex normals
// ---------------------------------------------------------------------------
__global__ __launch_bounds__(256) void k_face_sum(const float4* __restrict__ vn4,
                                                  const int* __restrict__ faces,
                                                  float4* __restrict__ fas4) {
    int i = blockIdx.x * 256 + threadIdx.x;
    if (i >= BB * NFF) return;
    int b = i / NFF;
    int f = i - b * NFF;
    int i0 = faces[3 * f + 0], i1 = faces[3 * f + 1], i2 = faces[3 * f + 2];
    const float4* vnb = vn4 + (size_t)b * VV;
    float4 a = vnb[i0], bb = vnb[i1], cc = vnb[i2];
    float4 o;
    o.x = a.x + bb.x + cc.x;
    o.y = a.y + bb.y + cc.y;
    o.z = a.z + bb.z + cc.z;
    o.w = 0.f;
    fas4[i] = o;
}

// ---------------------------------------------------------------------------
// Per-pixel gather + normalize + alpha. 8 px/thread, branchless clamped
// gather (8 independent L2 gathers in flight), NT stores on the 64 MB output.
// ---------------------------------------------------------------------------
__device__ __forceinline__ nf4 pixel_one(int f, float d, const float4* __restrict__ fasb) {
    int fc = f < 0 ? 0 : (f < (NFF - 1) ? f : (NFF - 1));
    float m = (f >= 0) ? 1.0f : 0.0f;
    float4 p = fasb[fc];
    float px = p.x * m, py = p.y * m, pz = p.z * m;
    float prob = m * __builtin_amdgcn_rcpf(1.0f + __expf(d * 1.0e4f));  // sigmoid(-d/SIGMA)*mask
    float n2 = px * px + py * py + pz * pz;
    float inv = __builtin_amdgcn_rcpf(fmaxf(sqrtf(n2), 1e-12f));
    float hitadd = (n2 > 0.f) ? 0.f : 1.0f;
    nf4 o;
    o.x = px * inv + hitadd;
    o.y = py * inv + hitadd;
    o.z = pz * inv + hitadd;
    o.w = 1.0f - prob;
    return o;
}

__global__ __launch_bounds__(256) void k_pixel(const int* __restrict__ p2f,
                                               const float* __restrict__ dists,
                                               const float4* __restrict__ fas4,
                                               nf4* __restrict__ out) {
    int i = (blockIdx.x * 256 + threadIdx.x) * 8;
    if (i >= BB * HH * WW) return;
    int b = i >> 18;  // H*W = 2^18; 8-px group never crosses batch boundary
    ni4 f0 = *(const ni4*)(p2f + i);
    ni4 f1 = *(const ni4*)(p2f + i + 4);
    nf4 d0 = *(const nf4*)(dists + i);
    nf4 d1 = *(const nf4*)(dists + i + 4);
    const float4* fasb = fas4 + (size_t)b * NFF;
    nf4 o0 = pixel_one(f0.x, d0.x, fasb);
    nf4 o1 = pixel_one(f0.y, d0.y, fasb);
    nf4 o2 = pixel_one(f0.z, d0.z, fasb);
    nf4 o3 = pixel_one(f0.w, d0.w, fasb);
    nf4 o4 = pixel_one(f1.x, d1.x, fasb);
    nf4 o5 = pixel_one(f1.y, d1.y, fasb);
    nf4 o6 = pixel_one(f1.z, d1.z, fasb);
    nf4 o7 = pixel_one(f1.w, d1.w, fasb);
    __builtin_nontemporal_store(o0, &out[i]);
    __builtin_nontemporal_store(o1, &out[i + 1]);
    __builtin_nontemporal_store(o2, &out[i + 2]);
    __builtin_nontemporal_store(o3, &out[i + 3]);
    __builtin_nontemporal_store(o4, &out[i + 4]);
    __builtin_nontemporal_store(o5, &out[i + 5]);
    __builtin_nontemporal_store(o6, &out[i + 6]);
    __builtin_nontemporal_store(o7, &out[i + 7]);
}

// ---------------------------------------------------------------------------
extern "C" void kernel_launch(void* const* d_in, const int* in_sizes, int n_in,
                              void* d_out, int out_size, void* d_ws, size_t ws_size,
                              hipStream_t stream) {
    const float* verts = (const float*)d_in[0];
    // d_in[1] = zbuf: dead in the reference's returned value -> never read
    const float* dists = (const float*)d_in[2];
    const int* faces   = (const int*)d_in[3];
    const int* p2f     = (const int*)d_in[4];

    // Workspace layout (16B-aligned chunks)
    char* w = (char*)d_ws;
    float4* fn4  = (float4*)w;  w += (size_t)BB * NFF * 16;    // 3.53 MB
    float4* vn4  = (float4*)w;  w += (size_t)BB * VV * 16;     // 1.76 MB
    float4* fas4 = (float4*)w;  w += (size_t)BB * NFF * 16;    // 3.53 MB
    int* offsets = (int*)w;     w += ((VV + 1) * 4 + 12) / 16 * 16;
    int* adj     = (int*)w;     w += NFF * 3 * 4;

    int nbf = BB * NFF;  // 220416
    int nbv = BB * VV;   // 110240

    int geo_blocks = 1 + (nbf + GEOT - 1) / GEOT;  // 1 CSR block + 216 fn blocks
    k_geo<<<geo_blocks, GEOT, 0, stream>>>(verts, faces, fn4, offsets, adj);
    k_vn<<<(nbv + 255) / 256, 256, 0, stream>>>(fn4, offsets, adj, vn4);
    k_face_sum<<<(nbf + 255) / 256, 256, 0, stream>>>(vn4, faces, fas4);

    int npix = BB * HH * WW;  // 4,194,304
    k_pixel<<<npix / 8 / 256, 256, 0, stream>>>(p2f, dists, fas4, (nf4*)d_out);
}

// Round 7
// 208.300 us; speedup vs baseline: 1.4141x; 1.4141x over previous
//
#include <hip/hip_runtime.h>
#include <math.h>

// Problem constants (from reference)
#define BB 16
#define VV 6890
#define NFF 13776
#define HH 512
#define WW 512
// SIGMA = 1e-4 -> 1/SIGMA = 1e4

typedef float nf4 __attribute__((ext_vector_type(4)));
typedef int   ni4 __attribute__((ext_vector_type(4)));

#define GEOT 1024

// ---------------------------------------------------------------------------
// Dispatch 1: block 0 builds vertex->face CSR entirely in LDS (histogram ->
// scan -> fill; no global atomics). Blocks 1..216 compute all B*NF face
// normals -> fn4. Independent work fused into one dispatch.
// NOTE: no cooperative launch -- hipLaunchCooperativeKernel is silently not
// captured by hipGraph in this harness (R6: replay diverged, launch ok).
// ---------------------------------------------------------------------------
__global__ __launch_bounds__(GEOT) void k_csr_fn(const float* __restrict__ verts,
                                                 const int* __restrict__ faces,
                                                 float4* __restrict__ fn4,
                                                 int* __restrict__ offsets,
                                                 int* __restrict__ adj) {
    int blk = blockIdx.x;
    int t = threadIdx.x;
    if (blk == 0) {
        __shared__ int hist[VV];      // 27.6 KB
        __shared__ int part[GEOT];    // 4 KB
        for (int v = t; v < VV; v += GEOT) hist[v] = 0;
        __syncthreads();
        for (int e = t; e < NFF * 3; e += GEOT) atomicAdd(&hist[faces[e]], 1);
        __syncthreads();
        const int CH = (VV + GEOT - 1) / GEOT;  // 7
        int base = t * CH;
        int local = 0;
        for (int k = 0; k < CH; k++) { int idx = base + k; if (idx < VV) local += hist[idx]; }
        part[t] = local;
        __syncthreads();
        for (int off = 1; off < GEOT; off <<= 1) {
            int v = part[t];
            int add = (t >= off) ? part[t - off] : 0;
            __syncthreads();
            part[t] = v + add;
            __syncthreads();
        }
        int running = (t == 0) ? 0 : part[t - 1];
        for (int k = 0; k < CH; k++) {
            int idx = base + k;
            if (idx < VV) {
                int c = hist[idx];
                hist[idx] = running;      // becomes the fill cursor
                offsets[idx] = running;
                running += c;
            }
        }
        if (t == 0) offsets[VV] = NFF * 3;
        __syncthreads();
        for (int e = t; e < NFF * 3; e += GEOT) {
            int v = faces[e];
            int pos = atomicAdd(&hist[v], 1);
            adj[pos] = e / 3;  // face id
        }
    } else {
        int i = (blk - 1) * GEOT + t;
        if (i >= BB * NFF) return;
        int b = i / NFF;
        int f = i - b * NFF;
        int i0 = faces[3 * f + 0];
        int i1 = faces[3 * f + 1];
        int i2 = faces[3 * f + 2];
        const float* vb = verts + (size_t)b * (VV * 3);
        float ax = vb[3 * i0 + 0], ay = vb[3 * i0 + 1], az = vb[3 * i0 + 2];
        float bx = vb[3 * i1 + 0], by = vb[3 * i1 + 1], bz = vb[3 * i1 + 2];
        float cx = vb[3 * i2 + 0], cy = vb[3 * i2 + 1], cz = vb[3 * i2 + 2];
        float e1x = bx - ax, e1y = by - ay, e1z = bz - az;
        float e2x = cx - ax, e2y = cy - ay, e2z = cz - az;
        float4 n;
        n.x = e1y * e2z - e1z * e2y;
        n.y = e1z * e2x - e1x * e2z;
        n.z = e1x * e2y - e1y * e2x;
        n.w = 0.f;
        fn4[i] = n;
    }
}

// ---------------------------------------------------------------------------
// Dispatch 2: face_attr_sum directly. Per-(b,f): recompute the 3 vertex
// normals by CSR-gathering fn4 (L2-resident, ~6x redundant -- cheaper than a
// separate vn kernel + extra launch). fas4[b,f] = sum of 3 normalized vn.
// ---------------------------------------------------------------------------
__device__ __forceinline__ void vn_accum(int v, const int* __restrict__ offsets,
                                         const int* __restrict__ adj,
                                         const float4* __restrict__ fnb,
                                         float& ox, float& oy, float& oz) {
    int s = offsets[v], e = offsets[v + 1];
    float x = 0.f, y = 0.f, z = 0.f;
    for (int j = s; j < e; j++) {
        float4 n = fnb[adj[j]];
        x += n.x; y += n.y; z += n.z;
    }
    float inv = 1.0f / fmaxf(sqrtf(x * x + y * y + z * z), 1e-6f);
    ox += x * inv; oy += y * inv; oz += z * inv;
}

__global__ __launch_bounds__(256) void k_fas(const float4* __restrict__ fn4,
                                             const int* __restrict__ faces,
                                             const int* __restrict__ offsets,
                                             const int* __restrict__ adj,
                                             float4* __restrict__ fas4) {
    int i = blockIdx.x * 256 + threadIdx.x;
    if (i >= BB * NFF) return;
    int b = i / NFF;
    int f = i - b * NFF;
    const float4* fnb = fn4 + (size_t)b * NFF;
    float ox = 0.f, oy = 0.f, oz = 0.f;
    vn_accum(faces[3 * f + 0], offsets, adj, fnb, ox, oy, oz);
    vn_accum(faces[3 * f + 1], offsets, adj, fnb, ox, oy, oz);
    vn_accum(faces[3 * f + 2], offsets, adj, fnb, ox, oy, oz);
    float4 o; o.x = ox; o.y = oy; o.z = oz; o.w = 0.f;
    fas4[i] = o;
}

// ---------------------------------------------------------------------------
// Dispatch 3: per-pixel gather + normalize + alpha. 4 px/thread, branchless
// clamped gather, PLAIN loads/stores (NT stores at wide lane stride gave 4x
// write amplification in R5: WRITE_SIZE 285MB vs 70MB).
// ---------------------------------------------------------------------------
__device__ __forceinline__ float4 pixel_one(int f, float d, const float4* __restrict__ fasb) {
    int fc = f < 0 ? 0 : (f < (NFF - 1) ? f : (NFF - 1));
    float m = (f >= 0) ? 1.0f : 0.0f;
    float4 p = fasb[fc];
    float px = p.x * m, py = p.y * m, pz = p.z * m;
    float prob = m * __builtin_amdgcn_rcpf(1.0f + __expf(d * 1.0e4f));  // sigmoid(-d/SIGMA)*mask
    float n2 = px * px + py * py + pz * pz;
    float inv = __builtin_amdgcn_rcpf(fmaxf(sqrtf(n2), 1e-12f));
    float hitadd = (n2 > 0.f) ? 0.f : 1.0f;
    float4 o;
    o.x = px * inv + hitadd;
    o.y = py * inv + hitadd;
    o.z = pz * inv + hitadd;
    o.w = 1.0f - prob;
    return o;
}

__global__ __launch_bounds__(256) void k_pixel(const int* __restrict__ p2f,
                                               const float* __restrict__ dists,
                                               const float4* __restrict__ fas4,
                                               float4* __restrict__ out) {
    int i = (blockIdx.x * 256 + threadIdx.x) * 4;
    if (i >= BB * HH * WW) return;
    int b = i >> 18;  // H*W = 2^18; quad never crosses batch boundary
    ni4 ff = *(const ni4*)(p2f + i);
    nf4 dd = *(const nf4*)(dists + i);
    const float4* fasb = fas4 + (size_t)b * NFF;
    float4 o0 = pixel_one(ff.x, dd.x, fasb);
    float4 o1 = pixel_one(ff.y, dd.y, fasb);
    float4 o2 = pixel_one(ff.z, dd.z, fasb);
    float4 o3 = pixel_one(ff.w, dd.w, fasb);
    out[i]     = o0;
    out[i + 1] = o1;
    out[i + 2] = o2;
    out[i + 3] = o3;
}

// ---------------------------------------------------------------------------
extern "C" void kernel_launch(void* const* d_in, const int* in_sizes, int n_in,
                              void* d_out, int out_size, void* d_ws, size_t ws_size,
                              hipStream_t stream) {
    const float* verts = (const float*)d_in[0];
    // d_in[1] = zbuf: dead in the reference's returned value -> never read
    const float* dists = (const float*)d_in[2];
    const int* faces   = (const int*)d_in[3];
    const int* p2f     = (const int*)d_in[4];

    // Workspace layout (16B-aligned chunks)
    char* w = (char*)d_ws;
    float4* fn4  = (float4*)w;  w += (size_t)BB * NFF * 16;    // 3.53 MB
    float4* fas4 = (float4*)w;  w += (size_t)BB * NFF * 16;    // 3.53 MB
    int* offsets = (int*)w;     w += ((VV + 1) * 4 + 12) / 16 * 16;
    int* adj     = (int*)w;     w += NFF * 3 * 4;

    int nbf = BB * NFF;  // 220416
    int geo_blocks = 1 + (nbf + GEOT - 1) / GEOT;  // 217
    k_csr_fn<<<geo_blocks, GEOT, 0, stream>>>(verts, faces, fn4, offsets, adj);
    k_fas<<<(nbf + 255) / 256, 256, 0, stream>>>(fn4, faces, offsets, adj, fas4);

    int npix = BB * HH * WW;  // 4,194,304
    k_pixel<<<npix / 4 / 256, 256, 0, stream>>>(p2f, dists, fas4, (float4*)d_out);
}

// Round 8
// 200.173 us; speedup vs baseline: 1.4715x; 1.0406x over previous
//
#include <hip/hip_runtime.h>
#include <math.h>

// Problem constants (from reference)
#define BB 16
#define VV 6890
#define NFF 13776
#define HH 512
#define WW 512
// SIGMA = 1e-4 -> 1/SIGMA = 1e4

typedef float nf4 __attribute__((ext_vector_type(4)));
typedef int   ni4 __attribute__((ext_vector_type(4)));
typedef _Float16 h4 __attribute__((ext_vector_type(4)));

// ---------------------------------------------------------------------------
// k_csr: ONE block builds the vertex->face CSR entirely in LDS.
// Isolated as its own dispatch so its true cost shows up in the profile.
// ---------------------------------------------------------------------------
#define CSRT 1024
__global__ __launch_bounds__(CSRT) void k_csr(const int* __restrict__ faces,
                                              int* __restrict__ offsets,
                                              int* __restrict__ adj) {
    __shared__ int hist[VV];      // 27.6 KB
    __shared__ int part[CSRT];    // 4 KB
    int t = threadIdx.x;
    for (int v = t; v < VV; v += CSRT) hist[v] = 0;
    __syncthreads();
    for (int e = t; e < NFF * 3; e += CSRT) atomicAdd(&hist[faces[e]], 1);
    __syncthreads();
    const int CH = (VV + CSRT - 1) / CSRT;  // 7
    int base = t * CH;
    int local = 0;
    for (int k = 0; k < CH; k++) { int idx = base + k; if (idx < VV) local += hist[idx]; }
    part[t] = local;
    __syncthreads();
    for (int off = 1; off < CSRT; off <<= 1) {
        int v = part[t];
        int add = (t >= off) ? part[t - off] : 0;
        __syncthreads();
        part[t] = v + add;
        __syncthreads();
    }
    int running = (t == 0) ? 0 : part[t - 1];
    for (int k = 0; k < CH; k++) {
        int idx = base + k;
        if (idx < VV) {
            int c = hist[idx];
            hist[idx] = running;      // becomes the fill cursor
            offsets[idx] = running;
            running += c;
        }
    }
    if (t == 0) offsets[VV] = NFF * 3;
    __syncthreads();
    for (int e = t; e < NFF * 3; e += CSRT) {
        int v = faces[e];
        int pos = atomicAdd(&hist[v], 1);
        adj[pos] = e / 3;  // face id
    }
}

// ---------------------------------------------------------------------------
// k_fn: per-(batch,face) face normal -> fn4
// ---------------------------------------------------------------------------
__global__ __launch_bounds__(256) void k_fn(const float* __restrict__ verts,
                                            const int* __restrict__ faces,
                                            float4* __restrict__ fn4) {
    int i = blockIdx.x * 256 + threadIdx.x;
    if (i >= BB * NFF) return;
    int b = i / NFF;
    int f = i - b * NFF;
    int i0 = faces[3 * f + 0];
    int i1 = faces[3 * f + 1];
    int i2 = faces[3 * f + 2];
    const float* vb = verts + (size_t)b * (VV * 3);
    float ax = vb[3 * i0 + 0], ay = vb[3 * i0 + 1], az = vb[3 * i0 + 2];
    float bx = vb[3 * i1 + 0], by = vb[3 * i1 + 1], bz = vb[3 * i1 + 2];
    float cx = vb[3 * i2 + 0], cy = vb[3 * i2 + 1], cz = vb[3 * i2 + 2];
    float e1x = bx - ax, e1y = by - ay, e1z = bz - az;
    float e2x = cx - ax, e2y = cy - ay, e2z = cz - az;
    float4 n;
    n.x = e1y * e2z - e1z * e2y;
    n.y = e1z * e2x - e1x * e2z;
    n.z = e1x * e2y - e1y * e2x;
    n.w = 0.f;
    fn4[i] = n;
}

// ---------------------------------------------------------------------------
// k_vn: per-(batch,vertex) CSR gather of adjacent face normals + normalize.
// ---------------------------------------------------------------------------
__global__ __launch_bounds__(256) void k_vn(const float4* __restrict__ fn4,
                                            const int* __restrict__ offsets,
                                            const int* __restrict__ adj,
                                            float4* __restrict__ vn4) {
    int i = blockIdx.x * 256 + threadIdx.x;
    if (i >= BB * VV) return;
    int b = i / VV;
    int v = i - b * VV;
    int s = offsets[v], e = offsets[v + 1];
    float x = 0.f, y = 0.f, z = 0.f;
    const float4* fnb = fn4 + (size_t)b * NFF;
    // 2-wide batches: two independent adj loads then two independent fn loads
    int j = s;
    for (; j + 1 < e; j += 2) {
        int a0 = adj[j], a1 = adj[j + 1];
        float4 n0 = fnb[a0];
        float4 n1 = fnb[a1];
        x += n0.x + n1.x; y += n0.y + n1.y; z += n0.z + n1.z;
    }
    if (j < e) {
        float4 n = fnb[adj[j]];
        x += n.x; y += n.y; z += n.z;
    }
    float inv = 1.0f / fmaxf(sqrtf(x * x + y * y + z * z), 1e-6f);
    float4 o; o.x = x * inv; o.y = y * inv; o.z = z * inv; o.w = 0.f;
    vn4[i] = o;
}

// ---------------------------------------------------------------------------
// k_face_sum: fas4[b,f] = sum of 3 vertex normals (direct loads, no chase)
// ---------------------------------------------------------------------------
__global__ __launch_bounds__(256) void k_face_sum(const float4* __restrict__ vn4,
                                                  const int* __restrict__ faces,
                                                  float4* __restrict__ fas4) {
    int i = blockIdx.x * 256 + threadIdx.x;
    if (i >= BB * NFF) return;
    int b = i / NFF;
    int f = i - b * NFF;
    int i0 = faces[3 * f + 0], i1 = faces[3 * f + 1], i2 = faces[3 * f + 2];
    const float4* vnb = vn4 + (size_t)b * VV;
    float4 a = vnb[i0], bb = vnb[i1], cc = vnb[i2];
    float4 o;
    o.x = a.x + bb.x + cc.x;
    o.y = a.y + bb.y + cc.y;
    o.z = a.z + bb.z + cc.z;
    o.w = 0.f;
    fas4[i] = o;
}

// ---------------------------------------------------------------------------
// k_pixel: one block <-> one (batch, 4096-pixel chunk). Phase 1 stages the
// whole per-batch fas table into LDS as half4 (13776 x 8 B = 107.6 KB; gfx950
// LDS = 160 KiB/CU). Phase 2: 4 px/thread, gathers hit LDS (no L2 chase).
// Plain loads/stores (NT at wide lane stride = 4x write amp, R5).
// ---------------------------------------------------------------------------
#define PIXT 1024
#define PIXB 1024   // 64 blocks per batch * 16 batches

__global__ __launch_bounds__(PIXT) void k_pixel(const int* __restrict__ p2f,
                                                const float* __restrict__ dists,
                                                const float4* __restrict__ fas4,
                                                float4* __restrict__ out) {
    __shared__ h4 sfas[NFF];   // 110,208 B
    int blk = blockIdx.x;
    int t = threadIdx.x;
    int b = blk >> 6;          // 64 blocks per batch
    int chunk = blk & 63;

    const float4* fasb = fas4 + (size_t)b * NFF;
    for (int j = t; j < NFF; j += PIXT) {
        float4 p = fasb[j];
        h4 h;
        h.x = (_Float16)p.x; h.y = (_Float16)p.y; h.z = (_Float16)p.z; h.w = (_Float16)0.f;
        sfas[j] = h;
    }
    __syncthreads();

    int i = (b << 18) + (chunk << 12) + t * 4;   // 4 px/thread
    ni4 ff = *(const ni4*)(p2f + i);
    nf4 dd = *(const nf4*)(dists + i);

    float4 res[4];
    int   fi[4] = { ff.x, ff.y, ff.z, ff.w };
    float di[4] = { dd.x, dd.y, dd.z, dd.w };
#pragma unroll
    for (int c = 0; c < 4; c++) {
        int f = fi[c];
        int fc = f < 0 ? 0 : (f < (NFF - 1) ? f : (NFF - 1));
        float m = (f >= 0) ? 1.0f : 0.0f;
        h4 hp = sfas[fc];
        float px = (float)hp.x * m, py = (float)hp.y * m, pz = (float)hp.z * m;
        float prob = m * __builtin_amdgcn_rcpf(1.0f + __expf(di[c] * 1.0e4f));
        float n2 = px * px + py * py + pz * pz;
        float inv = __builtin_amdgcn_rcpf(fmaxf(sqrtf(n2), 1e-12f));
        float hitadd = (n2 > 0.f) ? 0.f : 1.0f;
        res[c].x = px * inv + hitadd;
        res[c].y = py * inv + hitadd;
        res[c].z = pz * inv + hitadd;
        res[c].w = 1.0f - prob;
    }
    out[i]     = res[0];
    out[i + 1] = res[1];
    out[i + 2] = res[2];
    out[i + 3] = res[3];
}

// ---------------------------------------------------------------------------
extern "C" void kernel_launch(void* const* d_in, const int* in_sizes, int n_in,
                              void* d_out, int out_size, void* d_ws, size_t ws_size,
                              hipStream_t stream) {
    const float* verts = (const float*)d_in[0];
    // d_in[1] = zbuf: dead in the reference's returned value -> never read
    const float* dists = (const float*)d_in[2];
    const int* faces   = (const int*)d_in[3];
    const int* p2f     = (const int*)d_in[4];

    // Workspace layout (16B-aligned chunks)
    char* w = (char*)d_ws;
    float4* fn4  = (float4*)w;  w += (size_t)BB * NFF * 16;    // 3.53 MB
    float4* vn4  = (float4*)w;  w += (size_t)BB * VV * 16;     // 1.76 MB
    float4* fas4 = (float4*)w;  w += (size_t)BB * NFF * 16;    // 3.53 MB
    int* offsets = (int*)w;     w += ((VV + 1) * 4 + 12) / 16 * 16;
    int* adj     = (int*)w;     w += NFF * 3 * 4;

    int nbf = BB * NFF;  // 220416
    int nbv = BB * VV;   // 110240

    k_csr<<<1, CSRT, 0, stream>>>(faces, offsets, adj);
    k_fn<<<(nbf + 255) / 256, 256, 0, stream>>>(verts, faces, fn4);
    k_vn<<<(nbv + 255) / 256, 256, 0, stream>>>(fn4, offsets, adj, vn4);
    k_face_sum<<<(nbf + 255) / 256, 256, 0, stream>>>(vn4, faces, fas4);

    k_pixel<<<PIXB, PIXT, 0, stream>>>(p2f, dists, fas4, (float4*)d_out);
}